// Round 21
// baseline (295.774 us; speedup 1.0000x reference)
//
#include <hip/hip_runtime.h>
#include <hip/hip_bf16.h>
#include <math.h>

#define N_CAND 524288
#define RB     128
#define NBLK   (N_CAND / RB)     // 4096 compute tiles
#define NG     1024              // groups: 4 compute + 1 copy block each
#define EMB    128
#define HID    256
#define BGR    2048

#define OUT_XS  262144                      // offset of X_states in out (floats)
#define OUT_P   (262144 + 134217728)        // offset of probs in out (floats)

typedef __attribute__((ext_vector_type(4))) float f32x4;
typedef __attribute__((ext_vector_type(8))) short bf16x8;
typedef __attribute__((ext_vector_type(4))) short bf16x4;
typedef unsigned short u16;

// Native convert (RNE): pairs compile to v_cvt_pk_bf16_f32.
__device__ __forceinline__ u16 f2bf(float f) {
  __hip_bfloat16 h = __float2bfloat16(f);
  return *reinterpret_cast<u16*>(&h);
}

// Raw barrier: waits LDS ops only (lgkmcnt), does NOT drain vmcnt.
__device__ __forceinline__ void bar_lgkm() {
  __builtin_amdgcn_sched_barrier(0);
  asm volatile("s_waitcnt lgkmcnt(0)" ::: "memory");
  __builtin_amdgcn_sched_barrier(0);
  __builtin_amdgcn_s_barrier();
  __builtin_amdgcn_sched_barrier(0);
}
__device__ __forceinline__ void bar_only() {
  __builtin_amdgcn_sched_barrier(0);
  __builtin_amdgcn_s_barrier();
  __builtin_amdgcn_sched_barrier(0);
}

// ---- K0: W1/W2/W3 (f32, [k][n]) -> MFMA-fragment-packed bf16 ----
// dst u16 index = ((L*16+nt)*8+ks)*512 + lane*8 + j  (lane = g*16+ml).
__global__ void k_prep(const float* __restrict__ W1, const float* __restrict__ W2,
                       const float* __restrict__ W3, u16* __restrict__ wt) {
  const int b = blockIdx.x;
  const int m = b >> 8;          // which matrix
  const int n = b & 255;         // output unit
  const int k = threadIdx.x;     // input unit
  const float* W = (m == 0) ? W1 : ((m == 1) ? W2 : W3);
  const int nt = n >> 4, ml = n & 15;
  const int ks = k >> 5, g = (k >> 3) & 3, j = k & 7;
  const int lane = g * 16 + ml;
  wt[(((m * 16 + nt) * 8 + ks) << 9) + lane * 8 + j] = f2bf(W[k * 256 + n]);
}

// One MLP layer on buf (in place): champion inner geometry.
// Wave w owns n in [w*32, w*32+32) for all 128 rows.
__device__ __forceinline__ void mlp_layer(
    int Lidx, u16* buf, const u16* __restrict__ wt, const float* bias_s,
    int w, int lane, int ml, int g, int wn0, int swz, int bofs)
{
  const char* wl = (const char*)wt +
      ((size_t)(Lidx * 16 + w * 2) * 8) * 1024 + lane * 16;
  const float* bs = bias_s + Lidx * HID;
  char* const hb  = (char*)buf;
  char* const hbr = hb + (size_t)ml * 512;

  f32x4 acc[2][8];   // [nf][rf] = 64 AGPR
  #pragma unroll
  for (int nf = 0; nf < 2; ++nf)
    #pragma unroll
    for (int rf = 0; rf < 8; ++rf)
      acc[nf][rf] = (f32x4){0.f, 0.f, 0.f, 0.f};

  __builtin_amdgcn_s_setprio(1);
  #pragma unroll
  for (int ks = 0; ks < 8; ++ks) {
    bf16x8 a[2];
    #pragma unroll
    for (int nf = 0; nf < 2; ++nf)
      a[nf] = *(const bf16x8*)(wl + (nf * 8 + ks) * 1024);       // 1KB coalesced
    #pragma unroll
    for (int rh = 0; rh < 2; ++rh) {
      bf16x8 bq[4];
      #pragma unroll
      for (int rj = 0; rj < 4; ++rj)
        bq[rj] = *(const bf16x8*)(hbr + (rh * 4 + rj) * 8192 + ((ks * 64) ^ bofs));
      #pragma unroll
      for (int nf = 0; nf < 2; ++nf)
        #pragma unroll
        for (int rj = 0; rj < 4; ++rj)
          acc[nf][rh * 4 + rj] = __builtin_amdgcn_mfma_f32_16x16x32_bf16(
              a[nf], bq[rj], acc[nf][rh * 4 + rj], 0, 0, 0);
    }
  }
  __builtin_amdgcn_s_setprio(0);
  bar_only();   // all reads of buf done -> safe to overwrite in place

  #pragma unroll
  for (int nf = 0; nf < 2; ++nf) {
    const int n0 = wn0 + nf * 16 + g * 4;
    const f32x4 bb = *(const f32x4*)(bs + n0);
    #pragma unroll
    for (int rf = 0; rf < 8; ++rf) {
      const int r = rf * 16 + ml;
      bf16x4 hv;
      #pragma unroll
      for (int q = 0; q < 4; ++q) {
        float x = acc[nf][rf][q] + bb[q];
        x = fmaxf(x, 0.f);
        hv[q] = (short)f2bf(x);
      }
      *(bf16x4*)(hb + r * 512 + ((n0 * 2) ^ swz)) = hv;
    }
  }
  bar_lgkm();
}

// ---- K1: heterogeneous blocks ----
// Group of 5 dispatch-consecutive blocks: sub 0..3 = compute tiles
// (champion MLP body, NO X_states stores), sub 4 = streaming copy block
// that writes those 4 tiles' X_states (nt) reading the same (L3-warm)
// cand/g_emb rows. Copy blocks use no LDS/MFMA -> a {compute, copy} pair
// on a CU overlaps HBM streaming with MFMA/LDS compute structurally.
__global__ __launch_bounds__(512, 4) void k_main(
    const float* __restrict__ g_emb, const float* __restrict__ cand,
    const int* __restrict__ bidx,
    const float* __restrict__ b1, const float* __restrict__ b2,
    const float* __restrict__ b3, const float* __restrict__ Wf,
    const float* __restrict__ bfp, const u16* __restrict__ wt,
    float* __restrict__ out)
{
  __shared__ __align__(16) u16 hbuf[RB * HID];   // 64 KB, chunk-XOR swizzled
  __shared__ float bias_s[3 * HID];
  __shared__ float bf_s;

  const int tid = threadIdx.x;
  const int gid = blockIdx.x / 5;
  const int sub = blockIdx.x % 5;

  if (sub == 4) {
    // ---- copy block: X_states for rows [gid*512, gid*512+512) ----
    const int kc    = tid & 31;    // 16B chunk within the 256-col row
    const int row0  = tid >> 5;    // 0..15
    const int rbase = gid * 512;
    if (kc < 16) {
      #pragma unroll 4
      for (int i = 0; i < 32; ++i) {
        const int r = rbase + row0 + i * 16;
        const int b = bidx[r];
        const float* src = g_emb + (size_t)b * EMB + kc * 8;
        f32x4 v0 = *(const f32x4*)src;
        f32x4 v1 = *(const f32x4*)(src + 4);
        float* dst = out + OUT_XS + (size_t)r * (2 * EMB) + kc * 8;
        __builtin_nontemporal_store(v0, (f32x4*)dst);
        __builtin_nontemporal_store(v1, (f32x4*)(dst + 4));
      }
    } else {
      #pragma unroll 4
      for (int i = 0; i < 32; ++i) {
        const int r = rbase + row0 + i * 16;
        const float* src = cand + (size_t)r * EMB + (kc - 16) * 8;
        f32x4 v0 = *(const f32x4*)src;
        f32x4 v1 = *(const f32x4*)(src + 4);
        float* dst = out + OUT_XS + (size_t)r * (2 * EMB) + kc * 8;
        __builtin_nontemporal_store(v0, (f32x4*)dst);
        __builtin_nontemporal_store(v1, (f32x4*)(dst + 4));
      }
    }
    return;
  }

  // ---- compute block: tile = gid*4 + sub ----
  const int r0 = (gid * 4 + sub) * RB;

  if (tid < HID) {
    bias_s[tid]           = b1[tid];
    bias_s[HID + tid]     = b2[tid];
    bias_s[2 * HID + tid] = b3[tid];
    if (tid == 0) bf_s = bfp[0];
  }

  // ---- stage X (concat) into LDS bf16 swizzled (no global stores) ----
  {
    const int kc   = tid & 31;    // 16B chunk (8 elems) within the 256-col row
    const int row0 = tid >> 5;    // 0..15
    char* l0 = (char*)hbuf;
    int bpre[8];
    #pragma unroll
    for (int i = 0; i < 8; ++i)
      bpre[i] = bidx[r0 + row0 + i * 16];   // break dependent-load chain
    #pragma unroll
    for (int i = 0; i < 8; ++i) {
      const int row = row0 + i * 16;        // 0..127
      const int r   = r0 + row;
      const float* src = (kc < 16)
          ? g_emb + (size_t)bpre[i] * EMB + kc * 8
          : cand  + (size_t)r * EMB + (kc - 16) * 8;
      f32x4 v0 = *(const f32x4*)(src);
      f32x4 v1 = *(const f32x4*)(src + 4);
      bf16x8 hv;
      hv[0] = (short)f2bf(v0.x); hv[1] = (short)f2bf(v0.y);
      hv[2] = (short)f2bf(v0.z); hv[3] = (short)f2bf(v0.w);
      hv[4] = (short)f2bf(v1.x); hv[5] = (short)f2bf(v1.y);
      hv[6] = (short)f2bf(v1.z); hv[7] = (short)f2bf(v1.w);
      *(bf16x8*)(l0 + row * 512 + ((kc * 16) ^ ((row & 15) << 4))) = hv;
    }
  }
  bar_lgkm();

  const int lane = tid & 63;
  const int w    = tid >> 6;          // 0..7
  const int ml   = lane & 15;
  const int g    = lane >> 4;         // 0..3
  const int wn0  = w * 32;            // n-offset: 2 tiles of 16 per wave

  const int swz  = ml << 4;                 // row-swizzle ((rf*16+ml)&15 == ml)
  const int bofs = (g * 16) ^ swz;          // k-chunk xor per lane
  char* const hb  = (char*)hbuf;
  const char* const hbr = hb + (size_t)ml * 512;  // B-read base

  mlp_layer(0, hbuf, wt, bias_s, w, lane, ml, g, wn0, swz, bofs);
  mlp_layer(1, hbuf, wt, bias_s, w, lane, ml, g, wn0, swz, bofs);

  // ---- layer 3 + head, fused: h3 stays in registers ----
  {
    const char* wl = (const char*)wt +
        ((size_t)(2 * 16 + w * 2) * 8) * 1024 + lane * 16;

    f32x4 acc[2][8];
    #pragma unroll
    for (int nf = 0; nf < 2; ++nf)
      #pragma unroll
      for (int rf = 0; rf < 8; ++rf)
        acc[nf][rf] = (f32x4){0.f, 0.f, 0.f, 0.f};

    __builtin_amdgcn_s_setprio(1);
    #pragma unroll
    for (int ks = 0; ks < 8; ++ks) {
      bf16x8 a[2];
      #pragma unroll
      for (int nf = 0; nf < 2; ++nf)
        a[nf] = *(const bf16x8*)(wl + (nf * 8 + ks) * 1024);
      #pragma unroll
      for (int rh = 0; rh < 2; ++rh) {
        bf16x8 bq[4];
        #pragma unroll
        for (int rj = 0; rj < 4; ++rj)
          bq[rj] = *(const bf16x8*)(hbr + (rh * 4 + rj) * 8192 + ((ks * 64) ^ bofs));
        #pragma unroll
        for (int nf = 0; nf < 2; ++nf)
          #pragma unroll
          for (int rj = 0; rj < 4; ++rj)
            acc[nf][rh * 4 + rj] = __builtin_amdgcn_mfma_f32_16x16x32_bf16(
                a[nf], bq[rj], acc[nf][rh * 4 + rj], 0, 0, 0);
      }
    }
    __builtin_amdgcn_s_setprio(0);
    bar_only();   // all h2 reads done -> hbuf reusable as reduction pad

    // load wf/bias fragments AFTER the barrier (short liveness, no spill)
    const float* bs = bias_s + 2 * HID;
    const f32x4 bb0 = *(const f32x4*)(bs + wn0 + g * 4);
    const f32x4 bb1 = *(const f32x4*)(bs + wn0 + 16 + g * 4);
    const f32x4 wf0 = *(const f32x4*)(Wf + wn0 + g * 4);
    const f32x4 wf1 = *(const f32x4*)(Wf + wn0 + 16 + g * 4);

    float* pad = (float*)hbuf;   // [128][32] f32 partials, slot-swizzled
    #pragma unroll
    for (int rf = 0; rf < 8; ++rf) {
      const int r = rf * 16 + ml;
      f32x4 x0 = acc[0][rf] + bb0;
      f32x4 x1 = acc[1][rf] + bb1;
      float p = 0.f;
      #pragma unroll
      for (int q = 0; q < 4; ++q) {
        p += fmaxf(x0[q], 0.f) * wf0[q];
        p += fmaxf(x1[q], 0.f) * wf1[q];
      }
      const int slot = (w * 4 + g) ^ ((r & 7) << 2);   // conflict-free banks
      pad[r * 32 + slot] = p;
    }
    bar_lgkm();

    // reduce: 4 threads per row sum 32 partials -> e = exp(logit)
    {
      const int row  = tid >> 2;   // 0..127
      const int part = tid & 3;
      const int sx   = (row & 7) << 2;
      f32x4 v0 = *(const f32x4*)(pad + row * 32 + ((part * 8) ^ sx));
      f32x4 v1 = *(const f32x4*)(pad + row * 32 + ((part * 8 + 4) ^ sx));
      float s = v0[0] + v0[1] + v0[2] + v0[3] + v1[0] + v1[1] + v1[2] + v1[3];
      s += __shfl_xor(s, 1);
      s += __shfl_xor(s, 2);
      if (part == 0)
        out[OUT_P + (size_t)(r0 + row)] = __expf(s + bf_s);
    }
  }
}

// ---- K2: fused segment softmax-denominator + divide + g_emb copy ----
__global__ __launch_bounds__(256) void k_soft(
    const float* __restrict__ g_emb, const int* __restrict__ bidx,
    float* __restrict__ out)
{
  const int b   = blockIdx.x;
  const int tid = threadIdx.x;
  __shared__ float ws[4];
  __shared__ float sden;

  int lo = 0, hi = N_CAND;
  while (lo < hi) { int m = (lo + hi) >> 1; if (bidx[m] < b) lo = m + 1; else hi = m; }
  int lo2 = lo, hi2 = N_CAND;
  while (lo2 < hi2) { int m = (lo2 + hi2) >> 1; if (bidx[m] < b + 1) lo2 = m + 1; else hi2 = m; }

  float s = 0.f;
  for (int i = lo + tid; i < lo2; i += 256) s += out[OUT_P + (size_t)i];
  #pragma unroll
  for (int off = 32; off > 0; off >>= 1) s += __shfl_down(s, off);
  if ((tid & 63) == 0) ws[tid >> 6] = s;
  __syncthreads();
  if (tid == 0) sden = ws[0] + ws[1] + ws[2] + ws[3];
  __syncthreads();
  const float d = sden;
  for (int i = lo + tid; i < lo2; i += 256)
    out[OUT_P + (size_t)i] = out[OUT_P + (size_t)i] / d;

  if (tid < 32) {
    f32x4 v = *(const f32x4*)(g_emb + (size_t)b * EMB + tid * 4);
    *(f32x4*)(out + (size_t)b * EMB + tid * 4) = v;
  }
}

extern "C" void kernel_launch(void* const* d_in, const int* in_sizes, int n_in,
                              void* d_out, int out_size, void* d_ws, size_t ws_size,
                              hipStream_t stream)
{
  const float* g_emb = (const float*)d_in[0];
  const float* cand  = (const float*)d_in[1];
  const float* W1    = (const float*)d_in[2];
  const float* b1    = (const float*)d_in[3];
  const float* W2    = (const float*)d_in[4];
  const float* b2    = (const float*)d_in[5];
  const float* W3    = (const float*)d_in[6];
  const float* b3    = (const float*)d_in[7];
  const float* Wf    = (const float*)d_in[8];
  const float* bfp   = (const float*)d_in[9];
  const int*   bidx  = (const int*)d_in[10];
  float* out = (float*)d_out;

  u16* wt = (u16*)d_ws;    // 3 * 128 KB packed bf16 weights

  k_prep <<<768, 256, 0, stream>>>(W1, W2, W3, wt);
  k_main <<<5 * NG, 512, 0, stream>>>(g_emb, cand, bidx, b1, b2, b3, Wf, bfp, wt, out);
  k_soft <<<BGR, 256, 0, stream>>>(g_emb, bidx, out);
}

// Round 22
// 288.323 us; speedup vs baseline: 1.0258x; 1.0258x over previous
//
#include <hip/hip_runtime.h>
#include <hip/hip_bf16.h>
#include <math.h>

#define N_CAND 524288
#define RB     128
#define NBLK   (N_CAND / RB)     // 4096
#define EMB    128
#define HID    256
#define BGR    2048

#define OUT_XS  262144                      // offset of X_states in out (floats)
#define OUT_P   (262144 + 134217728)        // offset of probs in out (floats)

typedef __attribute__((ext_vector_type(4))) float f32x4;
typedef __attribute__((ext_vector_type(8))) short bf16x8;
typedef __attribute__((ext_vector_type(4))) short bf16x4;
typedef unsigned short u16;

// Native convert (RNE): pairs compile to v_cvt_pk_bf16_f32.
__device__ __forceinline__ u16 f2bf(float f) {
  __hip_bfloat16 h = __float2bfloat16(f);
  return *reinterpret_cast<u16*>(&h);
}

// Raw barrier: waits LDS ops only (lgkmcnt), does NOT drain vmcnt.
// Global stores (X_states) keep flowing under later phases.
__device__ __forceinline__ void bar_lgkm() {
  __builtin_amdgcn_sched_barrier(0);
  asm volatile("s_waitcnt lgkmcnt(0)" ::: "memory");
  __builtin_amdgcn_sched_barrier(0);
  __builtin_amdgcn_s_barrier();
  __builtin_amdgcn_sched_barrier(0);
}
__device__ __forceinline__ void bar_only() {
  __builtin_amdgcn_sched_barrier(0);
  __builtin_amdgcn_s_barrier();
  __builtin_amdgcn_sched_barrier(0);
}

// ---- K0: W1/W2/W3 (f32, [k][n]) -> MFMA-fragment-packed bf16 ----
// dst u16 index = ((L*16+nt)*8+ks)*512 + lane*8 + j  (lane = g*16+ml).
// A wave's A-fragment load (nt,ks) is then 64 lanes x 16B = 1 KB contiguous.
__global__ void k_prep(const float* __restrict__ W1, const float* __restrict__ W2,
                       const float* __restrict__ W3, u16* __restrict__ wt) {
  const int b = blockIdx.x;
  const int m = b >> 8;          // which matrix
  const int n = b & 255;         // output unit
  const int k = threadIdx.x;     // input unit
  const float* W = (m == 0) ? W1 : ((m == 1) ? W2 : W3);
  const int nt = n >> 4, ml = n & 15;
  const int ks = k >> 5, g = (k >> 3) & 3, j = k & 7;
  const int lane = g * 16 + ml;
  wt[(((m * 16 + nt) * 8 + ks) << 9) + lane * 8 + j] = f2bf(W[k * 256 + n]);
}

// One MLP layer on buf (in place): champion inner geometry.
// Wave w owns n in [w*32, w*32+32) for all 128 rows.
__device__ __forceinline__ void mlp_layer(
    int Lidx, u16* buf, const u16* __restrict__ wt, const float* bias_s,
    int w, int lane, int ml, int g, int wn0, int swz, int bofs)
{
  const char* wl = (const char*)wt +
      ((size_t)(Lidx * 16 + w * 2) * 8) * 1024 + lane * 16;
  const float* bs = bias_s + Lidx * HID;
  char* const hb  = (char*)buf;
  char* const hbr = hb + (size_t)ml * 512;

  f32x4 acc[2][8];   // [nf][rf] = 64 AGPR
  #pragma unroll
  for (int nf = 0; nf < 2; ++nf)
    #pragma unroll
    for (int rf = 0; rf < 8; ++rf)
      acc[nf][rf] = (f32x4){0.f, 0.f, 0.f, 0.f};

  __builtin_amdgcn_s_setprio(1);
  #pragma unroll
  for (int ks = 0; ks < 8; ++ks) {
    bf16x8 a[2];
    #pragma unroll
    for (int nf = 0; nf < 2; ++nf)
      a[nf] = *(const bf16x8*)(wl + (nf * 8 + ks) * 1024);       // 1KB coalesced
    #pragma unroll
    for (int rh = 0; rh < 2; ++rh) {
      bf16x8 bq[4];
      #pragma unroll
      for (int rj = 0; rj < 4; ++rj)
        bq[rj] = *(const bf16x8*)(hbr + (rh * 4 + rj) * 8192 + ((ks * 64) ^ bofs));
      #pragma unroll
      for (int nf = 0; nf < 2; ++nf)
        #pragma unroll
        for (int rj = 0; rj < 4; ++rj)
          acc[nf][rh * 4 + rj] = __builtin_amdgcn_mfma_f32_16x16x32_bf16(
              a[nf], bq[rj], acc[nf][rh * 4 + rj], 0, 0, 0);
    }
  }
  __builtin_amdgcn_s_setprio(0);
  bar_only();   // all reads of buf done -> safe to overwrite in place

  #pragma unroll
  for (int nf = 0; nf < 2; ++nf) {
    const int n0 = wn0 + nf * 16 + g * 4;
    const f32x4 bb = *(const f32x4*)(bs + n0);
    #pragma unroll
    for (int rf = 0; rf < 8; ++rf) {
      const int r = rf * 16 + ml;
      bf16x4 hv;
      #pragma unroll
      for (int q = 0; q < 4; ++q) {
        float x = acc[nf][rf][q] + bb[q];
        x = fmaxf(x, 0.f);
        hv[q] = (short)f2bf(x);
      }
      *(bf16x4*)(hb + r * 512 + ((n0 * 2) ^ swz)) = hv;
    }
  }
  bar_lgkm();
}

// ---- K1: fused X-concat/X_states write + 3-layer MLP + fused head ----
// r16 champion + anti-phase stagger: blocks i and i+256 share a CU
// (XCD=i%8, CU=(i/8)%32); delaying the (i>>8)&1 partner by ~one stage
// phase breaks the barrier-cadence lockstep so one block's MFMA fills
// the other's stage/epilogue gaps.
__global__ __launch_bounds__(512, 4) void k_main(
    const float* __restrict__ g_emb, const float* __restrict__ cand,
    const int* __restrict__ bidx,
    const float* __restrict__ b1, const float* __restrict__ b2,
    const float* __restrict__ b3, const float* __restrict__ Wf,
    const float* __restrict__ bfp, const u16* __restrict__ wt,
    float* __restrict__ out)
{
  __shared__ __align__(16) u16 hbuf[RB * HID];   // 64 KB, chunk-XOR swizzled
  __shared__ float bias_s[3 * HID];
  __shared__ float bf_s;

  // anti-phase stagger (~6.8 us) for the second resident block on a CU
  if ((blockIdx.x >> 8) & 1) {
    #pragma unroll 1
    for (int i = 0; i < 2; ++i) __builtin_amdgcn_s_sleep(127);
  }

  const int tid = threadIdx.x;
  const int r0  = blockIdx.x * RB;

  if (tid < HID) {
    bias_s[tid]           = b1[tid];
    bias_s[HID + tid]     = b2[tid];
    bias_s[2 * HID + tid] = b3[tid];
    if (tid == 0) bf_s = bfp[0];
  }

  // ---- stage X (concat) into LDS bf16 swizzled; write X_states f32 (nt) ----
  {
    const int kc   = tid & 31;    // 16B chunk (8 elems) within the 256-col row
    const int row0 = tid >> 5;    // 0..15
    char* l0 = (char*)hbuf;
    int bpre[8];
    #pragma unroll
    for (int i = 0; i < 8; ++i)
      bpre[i] = bidx[r0 + row0 + i * 16];   // break dependent-load chain
    #pragma unroll
    for (int i = 0; i < 8; ++i) {
      const int row = row0 + i * 16;        // 0..127
      const int r   = r0 + row;
      const float* src = (kc < 16)
          ? g_emb + (size_t)bpre[i] * EMB + kc * 8
          : cand  + (size_t)r * EMB + (kc - 16) * 8;
      f32x4 v0 = *(const f32x4*)(src);
      f32x4 v1 = *(const f32x4*)(src + 4);
      float* dst = out + OUT_XS + (size_t)r * (2 * EMB) + kc * 8;
      __builtin_nontemporal_store(v0, (f32x4*)dst);        // nt: no cache alloc
      __builtin_nontemporal_store(v1, (f32x4*)(dst + 4));  // fire-and-forget
      bf16x8 hv;
      hv[0] = (short)f2bf(v0.x); hv[1] = (short)f2bf(v0.y);
      hv[2] = (short)f2bf(v0.z); hv[3] = (short)f2bf(v0.w);
      hv[4] = (short)f2bf(v1.x); hv[5] = (short)f2bf(v1.y);
      hv[6] = (short)f2bf(v1.z); hv[7] = (short)f2bf(v1.w);
      *(bf16x8*)(l0 + row * 512 + ((kc * 16) ^ ((row & 15) << 4))) = hv;
    }
  }
  bar_lgkm();

  const int lane = tid & 63;
  const int w    = tid >> 6;          // 0..7
  const int ml   = lane & 15;
  const int g    = lane >> 4;         // 0..3
  const int wn0  = w * 32;            // n-offset: 2 tiles of 16 per wave

  const int swz  = ml << 4;                 // row-swizzle ((rf*16+ml)&15 == ml)
  const int bofs = (g * 16) ^ swz;          // k-chunk xor per lane
  char* const hb  = (char*)hbuf;
  const char* const hbr = hb + (size_t)ml * 512;  // B-read base

  mlp_layer(0, hbuf, wt, bias_s, w, lane, ml, g, wn0, swz, bofs);
  mlp_layer(1, hbuf, wt, bias_s, w, lane, ml, g, wn0, swz, bofs);

  // ---- layer 3 + head, fused: h3 stays in registers ----
  {
    const char* wl = (const char*)wt +
        ((size_t)(2 * 16 + w * 2) * 8) * 1024 + lane * 16;

    f32x4 acc[2][8];
    #pragma unroll
    for (int nf = 0; nf < 2; ++nf)
      #pragma unroll
      for (int rf = 0; rf < 8; ++rf)
        acc[nf][rf] = (f32x4){0.f, 0.f, 0.f, 0.f};

    __builtin_amdgcn_s_setprio(1);
    #pragma unroll
    for (int ks = 0; ks < 8; ++ks) {
      bf16x8 a[2];
      #pragma unroll
      for (int nf = 0; nf < 2; ++nf)
        a[nf] = *(const bf16x8*)(wl + (nf * 8 + ks) * 1024);
      #pragma unroll
      for (int rh = 0; rh < 2; ++rh) {
        bf16x8 bq[4];
        #pragma unroll
        for (int rj = 0; rj < 4; ++rj)
          bq[rj] = *(const bf16x8*)(hbr + (rh * 4 + rj) * 8192 + ((ks * 64) ^ bofs));
        #pragma unroll
        for (int nf = 0; nf < 2; ++nf)
          #pragma unroll
          for (int rj = 0; rj < 4; ++rj)
            acc[nf][rh * 4 + rj] = __builtin_amdgcn_mfma_f32_16x16x32_bf16(
                a[nf], bq[rj], acc[nf][rh * 4 + rj], 0, 0, 0);
      }
    }
    __builtin_amdgcn_s_setprio(0);
    bar_only();   // all h2 reads done -> hbuf reusable as reduction pad

    // load wf/bias fragments AFTER the barrier (short liveness, no spill)
    const float* bs = bias_s + 2 * HID;
    const f32x4 bb0 = *(const f32x4*)(bs + wn0 + g * 4);
    const f32x4 bb1 = *(const f32x4*)(bs + wn0 + 16 + g * 4);
    const f32x4 wf0 = *(const f32x4*)(Wf + wn0 + g * 4);
    const f32x4 wf1 = *(const f32x4*)(Wf + wn0 + 16 + g * 4);

    float* pad = (float*)hbuf;   // [128][32] f32 partials, slot-swizzled
    #pragma unroll
    for (int rf = 0; rf < 8; ++rf) {
      const int r = rf * 16 + ml;
      f32x4 x0 = acc[0][rf] + bb0;
      f32x4 x1 = acc[1][rf] + bb1;
      float p = 0.f;
      #pragma unroll
      for (int q = 0; q < 4; ++q) {
        p += fmaxf(x0[q], 0.f) * wf0[q];
        p += fmaxf(x1[q], 0.f) * wf1[q];
      }
      const int slot = (w * 4 + g) ^ ((r & 7) << 2);   // conflict-free banks
      pad[r * 32 + slot] = p;
    }
    bar_lgkm();

    // reduce: 4 threads per row sum 32 partials -> e = exp(logit)
    {
      const int row  = tid >> 2;   // 0..127
      const int part = tid & 3;
      const int sx   = (row & 7) << 2;
      f32x4 v0 = *(const f32x4*)(pad + row * 32 + ((part * 8) ^ sx));
      f32x4 v1 = *(const f32x4*)(pad + row * 32 + ((part * 8 + 4) ^ sx));
      float s = v0[0] + v0[1] + v0[2] + v0[3] + v1[0] + v1[1] + v1[2] + v1[3];
      s += __shfl_xor(s, 1);
      s += __shfl_xor(s, 2);
      if (part == 0)
        out[OUT_P + (size_t)(r0 + row)] = __expf(s + bf_s);
    }
  }
}

// ---- K2: fused segment softmax-denominator + divide + g_emb copy ----
__global__ __launch_bounds__(256) void k_soft(
    const float* __restrict__ g_emb, const int* __restrict__ bidx,
    float* __restrict__ out)
{
  const int b   = blockIdx.x;
  const int tid = threadIdx.x;
  __shared__ float ws[4];
  __shared__ float sden;

  int lo = 0, hi = N_CAND;
  while (lo < hi) { int m = (lo + hi) >> 1; if (bidx[m] < b) lo = m + 1; else hi = m; }
  int lo2 = lo, hi2 = N_CAND;
  while (lo2 < hi2) { int m = (lo2 + hi2) >> 1; if (bidx[m] < b + 1) lo2 = m + 1; else hi2 = m; }

  float s = 0.f;
  for (int i = lo + tid; i < lo2; i += 256) s += out[OUT_P + (size_t)i];
  #pragma unroll
  for (int off = 32; off > 0; off >>= 1) s += __shfl_down(s, off);
  if ((tid & 63) == 0) ws[tid >> 6] = s;
  __syncthreads();
  if (tid == 0) sden = ws[0] + ws[1] + ws[2] + ws[3];
  __syncthreads();
  const float d = sden;
  for (int i = lo + tid; i < lo2; i += 256)
    out[OUT_P + (size_t)i] = out[OUT_P + (size_t)i] / d;

  if (tid < 32) {
    f32x4 v = *(const f32x4*)(g_emb + (size_t)b * EMB + tid * 4);
    *(f32x4*)(out + (size_t)b * EMB + tid * 4) = v;
  }
}

extern "C" void kernel_launch(void* const* d_in, const int* in_sizes, int n_in,
                              void* d_out, int out_size, void* d_ws, size_t ws_size,
                              hipStream_t stream)
{
  const float* g_emb = (const float*)d_in[0];
  const float* cand  = (const float*)d_in[1];
  const float* W1    = (const float*)d_in[2];
  const float* b1    = (const float*)d_in[3];
  const float* W2    = (const float*)d_in[4];
  const float* b2    = (const float*)d_in[5];
  const float* W3    = (const float*)d_in[6];
  const float* b3    = (const float*)d_in[7];
  const float* Wf    = (const float*)d_in[8];
  const float* bfp   = (const float*)d_in[9];
  const int*   bidx  = (const int*)d_in[10];
  float* out = (float*)d_out;

  u16* wt = (u16*)d_ws;    // 3 * 128 KB packed bf16 weights

  k_prep <<<768, 256, 0, stream>>>(W1, W2, W3, wt);
  k_main <<<NBLK, 512, 0, stream>>>(g_emb, cand, bidx, b1, b2, b3, Wf, bfp, wt, out);
  k_soft <<<BGR, 256, 0, stream>>>(g_emb, bidx, out);
}

// Round 23
// 275.760 us; speedup vs baseline: 1.0726x; 1.0456x over previous
//
#include <hip/hip_runtime.h>
#include <hip/hip_bf16.h>
#include <math.h>

#define N_CAND 524288
#define RB     128
#define NBLK   (N_CAND / RB)     // 4096
#define EMB    128
#define HID    256
#define BGR    2048

#define OUT_XS  262144                      // offset of X_states in out (floats)
#define OUT_P   (262144 + 134217728)        // offset of probs in out (floats)

typedef __attribute__((ext_vector_type(4))) float f32x4;
typedef __attribute__((ext_vector_type(8))) short bf16x8;
typedef __attribute__((ext_vector_type(4))) short bf16x4;
typedef unsigned short u16;

// Native convert (RNE): pairs compile to v_cvt_pk_bf16_f32.
__device__ __forceinline__ u16 f2bf(float f) {
  __hip_bfloat16 h = __float2bfloat16(f);
  return *reinterpret_cast<u16*>(&h);
}

// Raw barrier: waits LDS ops only (lgkmcnt), does NOT drain vmcnt.
// Global stores (X_states) keep flowing under later phases.
__device__ __forceinline__ void bar_lgkm() {
  __builtin_amdgcn_sched_barrier(0);
  asm volatile("s_waitcnt lgkmcnt(0)" ::: "memory");
  __builtin_amdgcn_sched_barrier(0);
  __builtin_amdgcn_s_barrier();
  __builtin_amdgcn_sched_barrier(0);
}
__device__ __forceinline__ void bar_only() {
  __builtin_amdgcn_sched_barrier(0);
  __builtin_amdgcn_s_barrier();
  __builtin_amdgcn_sched_barrier(0);
}

// ---- K0: W1/W2/W3 (f32, [k][n]) -> MFMA-fragment-packed bf16 ----
// dst u16 index = ((L*16+nt)*8+ks)*512 + lane*8 + j  (lane = g*16+ml).
// A wave's A-fragment load (nt,ks) is then 64 lanes x 16B = 1 KB contiguous.
__global__ void k_prep(const float* __restrict__ W1, const float* __restrict__ W2,
                       const float* __restrict__ W3, u16* __restrict__ wt) {
  const int b = blockIdx.x;
  const int m = b >> 8;          // which matrix
  const int n = b & 255;         // output unit
  const int k = threadIdx.x;     // input unit
  const float* W = (m == 0) ? W1 : ((m == 1) ? W2 : W3);
  const int nt = n >> 4, ml = n & 15;
  const int ks = k >> 5, g = (k >> 3) & 3, j = k & 7;
  const int lane = g * 16 + ml;
  wt[(((m * 16 + nt) * 8 + ks) << 9) + lane * 8 + j] = f2bf(W[k * 256 + n]);
}

// One MLP layer on buf (in place): champion inner geometry.
// Wave w owns n in [w*32, w*32+32) for all 128 rows.
__device__ __forceinline__ void mlp_layer(
    int Lidx, u16* buf, const u16* __restrict__ wt, const float* bias_s,
    int w, int lane, int ml, int g, int wn0, int swz, int bofs)
{
  const char* wl = (const char*)wt +
      ((size_t)(Lidx * 16 + w * 2) * 8) * 1024 + lane * 16;
  const float* bs = bias_s + Lidx * HID;
  char* const hb  = (char*)buf;
  char* const hbr = hb + (size_t)ml * 512;

  f32x4 acc[2][8];   // [nf][rf] = 64 AGPR
  #pragma unroll
  for (int nf = 0; nf < 2; ++nf)
    #pragma unroll
    for (int rf = 0; rf < 8; ++rf)
      acc[nf][rf] = (f32x4){0.f, 0.f, 0.f, 0.f};

  __builtin_amdgcn_s_setprio(1);
  #pragma unroll
  for (int ks = 0; ks < 8; ++ks) {
    bf16x8 a[2];
    #pragma unroll
    for (int nf = 0; nf < 2; ++nf)
      a[nf] = *(const bf16x8*)(wl + (nf * 8 + ks) * 1024);       // 1KB coalesced
    #pragma unroll
    for (int rh = 0; rh < 2; ++rh) {
      bf16x8 bq[4];
      #pragma unroll
      for (int rj = 0; rj < 4; ++rj)
        bq[rj] = *(const bf16x8*)(hbr + (rh * 4 + rj) * 8192 + ((ks * 64) ^ bofs));
      #pragma unroll
      for (int nf = 0; nf < 2; ++nf)
        #pragma unroll
        for (int rj = 0; rj < 4; ++rj)
          acc[nf][rh * 4 + rj] = __builtin_amdgcn_mfma_f32_16x16x32_bf16(
              a[nf], bq[rj], acc[nf][rh * 4 + rj], 0, 0, 0);
    }
  }
  __builtin_amdgcn_s_setprio(0);
  bar_only();   // all reads of buf done -> safe to overwrite in place

  #pragma unroll
  for (int nf = 0; nf < 2; ++nf) {
    const int n0 = wn0 + nf * 16 + g * 4;
    const f32x4 bb = *(const f32x4*)(bs + n0);
    #pragma unroll
    for (int rf = 0; rf < 8; ++rf) {
      const int r = rf * 16 + ml;
      bf16x4 hv;
      #pragma unroll
      for (int q = 0; q < 4; ++q) {
        float x = acc[nf][rf][q] + bb[q];
        x = fmaxf(x, 0.f);
        hv[q] = (short)f2bf(x);
      }
      *(bf16x4*)(hb + r * 512 + ((n0 * 2) ^ swz)) = hv;
    }
  }
  bar_lgkm();
}

// ---- K1: fused X-concat/X_states write + 3-layer MLP + fused head ----
// r16 champion: 8 waves, RB=128, weights once/block, packed 1KB A-loads,
// lgkm-only barriers, NON-TEMPORAL X_states stores (the write stream
// bypasses L2/L3 allocation and stops evicting cand/weights).
__global__ __launch_bounds__(512, 4) void k_main(
    const float* __restrict__ g_emb, const float* __restrict__ cand,
    const int* __restrict__ bidx,
    const float* __restrict__ b1, const float* __restrict__ b2,
    const float* __restrict__ b3, const float* __restrict__ Wf,
    const float* __restrict__ bfp, const u16* __restrict__ wt,
    float* __restrict__ out)
{
  __shared__ __align__(16) u16 hbuf[RB * HID];   // 64 KB, chunk-XOR swizzled
  __shared__ float bias_s[3 * HID];
  __shared__ float bf_s;

  const int tid = threadIdx.x;
  const int r0  = blockIdx.x * RB;

  if (tid < HID) {
    bias_s[tid]           = b1[tid];
    bias_s[HID + tid]     = b2[tid];
    bias_s[2 * HID + tid] = b3[tid];
    if (tid == 0) bf_s = bfp[0];
  }

  // ---- stage X (concat) into LDS bf16 swizzled; write X_states f32 (nt) ----
  {
    const int kc   = tid & 31;    // 16B chunk (8 elems) within the 256-col row
    const int row0 = tid >> 5;    // 0..15
    char* l0 = (char*)hbuf;
    int bpre[8];
    #pragma unroll
    for (int i = 0; i < 8; ++i)
      bpre[i] = bidx[r0 + row0 + i * 16];   // break dependent-load chain
    #pragma unroll
    for (int i = 0; i < 8; ++i) {
      const int row = row0 + i * 16;        // 0..127
      const int r   = r0 + row;
      const float* src = (kc < 16)
          ? g_emb + (size_t)bpre[i] * EMB + kc * 8
          : cand  + (size_t)r * EMB + (kc - 16) * 8;
      f32x4 v0 = *(const f32x4*)(src);
      f32x4 v1 = *(const f32x4*)(src + 4);
      float* dst = out + OUT_XS + (size_t)r * (2 * EMB) + kc * 8;
      __builtin_nontemporal_store(v0, (f32x4*)dst);        // nt: no cache alloc
      __builtin_nontemporal_store(v1, (f32x4*)(dst + 4));  // fire-and-forget
      bf16x8 hv;
      hv[0] = (short)f2bf(v0.x); hv[1] = (short)f2bf(v0.y);
      hv[2] = (short)f2bf(v0.z); hv[3] = (short)f2bf(v0.w);
      hv[4] = (short)f2bf(v1.x); hv[5] = (short)f2bf(v1.y);
      hv[6] = (short)f2bf(v1.z); hv[7] = (short)f2bf(v1.w);
      *(bf16x8*)(l0 + row * 512 + ((kc * 16) ^ ((row & 15) << 4))) = hv;
    }
  }
  bar_lgkm();

  const int lane = tid & 63;
  const int w    = tid >> 6;          // 0..7
  const int ml   = lane & 15;
  const int g    = lane >> 4;         // 0..3
  const int wn0  = w * 32;            // n-offset: 2 tiles of 16 per wave

  const int swz  = ml << 4;                 // row-swizzle ((rf*16+ml)&15 == ml)
  const int bofs = (g * 16) ^ swz;          // k-chunk xor per lane
  char* const hb  = (char*)hbuf;
  const char* const hbr = hb + (size_t)ml * 512;  // B-read base

  mlp_layer(0, hbuf, wt, bias_s, w, lane, ml, g, wn0, swz, bofs);
  mlp_layer(1, hbuf, wt, bias_s, w, lane, ml, g, wn0, swz, bofs);

  // ---- layer 3 + head, fused: h3 stays in registers ----
  {
    const char* wl = (const char*)wt +
        ((size_t)(2 * 16 + w * 2) * 8) * 1024 + lane * 16;

    f32x4 acc[2][8];
    #pragma unroll
    for (int nf = 0; nf < 2; ++nf)
      #pragma unroll
      for (int rf = 0; rf < 8; ++rf)
        acc[nf][rf] = (f32x4){0.f, 0.f, 0.f, 0.f};

    __builtin_amdgcn_s_setprio(1);
    #pragma unroll
    for (int ks = 0; ks < 8; ++ks) {
      bf16x8 a[2];
      #pragma unroll
      for (int nf = 0; nf < 2; ++nf)
        a[nf] = *(const bf16x8*)(wl + (nf * 8 + ks) * 1024);
      #pragma unroll
      for (int rh = 0; rh < 2; ++rh) {
        bf16x8 bq[4];
        #pragma unroll
        for (int rj = 0; rj < 4; ++rj)
          bq[rj] = *(const bf16x8*)(hbr + (rh * 4 + rj) * 8192 + ((ks * 64) ^ bofs));
        #pragma unroll
        for (int nf = 0; nf < 2; ++nf)
          #pragma unroll
          for (int rj = 0; rj < 4; ++rj)
            acc[nf][rh * 4 + rj] = __builtin_amdgcn_mfma_f32_16x16x32_bf16(
                a[nf], bq[rj], acc[nf][rh * 4 + rj], 0, 0, 0);
      }
    }
    __builtin_amdgcn_s_setprio(0);
    bar_only();   // all h2 reads done -> hbuf reusable as reduction pad

    // load wf/bias fragments AFTER the barrier (short liveness, no spill)
    const float* bs = bias_s + 2 * HID;
    const f32x4 bb0 = *(const f32x4*)(bs + wn0 + g * 4);
    const f32x4 bb1 = *(const f32x4*)(bs + wn0 + 16 + g * 4);
    const f32x4 wf0 = *(const f32x4*)(Wf + wn0 + g * 4);
    const f32x4 wf1 = *(const f32x4*)(Wf + wn0 + 16 + g * 4);

    float* pad = (float*)hbuf;   // [128][32] f32 partials, slot-swizzled
    #pragma unroll
    for (int rf = 0; rf < 8; ++rf) {
      const int r = rf * 16 + ml;
      f32x4 x0 = acc[0][rf] + bb0;
      f32x4 x1 = acc[1][rf] + bb1;
      float p = 0.f;
      #pragma unroll
      for (int q = 0; q < 4; ++q) {
        p += fmaxf(x0[q], 0.f) * wf0[q];
        p += fmaxf(x1[q], 0.f) * wf1[q];
      }
      const int slot = (w * 4 + g) ^ ((r & 7) << 2);   // conflict-free banks
      pad[r * 32 + slot] = p;
    }
    bar_lgkm();

    // reduce: 4 threads per row sum 32 partials -> e = exp(logit)
    {
      const int row  = tid >> 2;   // 0..127
      const int part = tid & 3;
      const int sx   = (row & 7) << 2;
      f32x4 v0 = *(const f32x4*)(pad + row * 32 + ((part * 8) ^ sx));
      f32x4 v1 = *(const f32x4*)(pad + row * 32 + ((part * 8 + 4) ^ sx));
      float s = v0[0] + v0[1] + v0[2] + v0[3] + v1[0] + v1[1] + v1[2] + v1[3];
      s += __shfl_xor(s, 1);
      s += __shfl_xor(s, 2);
      if (part == 0)
        out[OUT_P + (size_t)(r0 + row)] = __expf(s + bf_s);
    }
  }
}

// ---- K2: fused segment softmax-denominator + divide + g_emb copy ----
__global__ __launch_bounds__(256) void k_soft(
    const float* __restrict__ g_emb, const int* __restrict__ bidx,
    float* __restrict__ out)
{
  const int b   = blockIdx.x;
  const int tid = threadIdx.x;
  __shared__ float ws[4];
  __shared__ float sden;

  int lo = 0, hi = N_CAND;
  while (lo < hi) { int m = (lo + hi) >> 1; if (bidx[m] < b) lo = m + 1; else hi = m; }
  int lo2 = lo, hi2 = N_CAND;
  while (lo2 < hi2) { int m = (lo2 + hi2) >> 1; if (bidx[m] < b + 1) lo2 = m + 1; else hi2 = m; }

  float s = 0.f;
  for (int i = lo + tid; i < lo2; i += 256) s += out[OUT_P + (size_t)i];
  #pragma unroll
  for (int off = 32; off > 0; off >>= 1) s += __shfl_down(s, off);
  if ((tid & 63) == 0) ws[tid >> 6] = s;
  __syncthreads();
  if (tid == 0) sden = ws[0] + ws[1] + ws[2] + ws[3];
  __syncthreads();
  const float d = sden;
  for (int i = lo + tid; i < lo2; i += 256)
    out[OUT_P + (size_t)i] = out[OUT_P + (size_t)i] / d;

  if (tid < 32) {
    f32x4 v = *(const f32x4*)(g_emb + (size_t)b * EMB + tid * 4);
    *(f32x4*)(out + (size_t)b * EMB + tid * 4) = v;
  }
}

extern "C" void kernel_launch(void* const* d_in, const int* in_sizes, int n_in,
                              void* d_out, int out_size, void* d_ws, size_t ws_size,
                              hipStream_t stream)
{
  const float* g_emb = (const float*)d_in[0];
  const float* cand  = (const float*)d_in[1];
  const float* W1    = (const float*)d_in[2];
  const float* b1    = (const float*)d_in[3];
  const float* W2    = (const float*)d_in[4];
  const float* b2    = (const float*)d_in[5];
  const float* W3    = (const float*)d_in[6];
  const float* b3    = (const float*)d_in[7];
  const float* Wf    = (const float*)d_in[8];
  const float* bfp   = (const float*)d_in[9];
  const int*   bidx  = (const int*)d_in[10];
  float* out = (float*)d_out;

  u16* wt = (u16*)d_ws;    // 3 * 128 KB packed bf16 weights

  k_prep <<<768, 256, 0, stream>>>(W1, W2, W3, wt);
  k_main <<<NBLK, 512, 0, stream>>>(g_emb, cand, bidx, b1, b2, b3, Wf, bfp, wt, out);
  k_soft <<<BGR, 256, 0, stream>>>(g_emb, bidx, out);
}

// Round 24
// 239.481 us; speedup vs baseline: 1.2351x; 1.1515x over previous
//
#include <hip/hip_runtime.h>
#include <hip/hip_bf16.h>
#include <math.h>

#define N_CAND 524288
#define RB     128
#define NBLK   (N_CAND / RB)     // 4096
#define EMB    128
#define HID    256
#define BGR    2048

#define OUT_XS  262144                      // offset of X_states in out (floats)
#define OUT_P   (262144 + 134217728)        // offset of probs in out (floats)

typedef __attribute__((ext_vector_type(4))) float f32x4;
typedef __attribute__((ext_vector_type(8))) short bf16x8;
typedef __attribute__((ext_vector_type(4))) short bf16x4;
typedef unsigned short u16;

// Native convert (RNE): pairs compile to v_cvt_pk_bf16_f32.
__device__ __forceinline__ u16 f2bf(float f) {
  __hip_bfloat16 h = __float2bfloat16(f);
  return *reinterpret_cast<u16*>(&h);
}

// Raw barrier: waits LDS ops only (lgkmcnt), does NOT drain vmcnt.
// Global stores (X_states) keep flowing under later phases.
__device__ __forceinline__ void bar_lgkm() {
  __builtin_amdgcn_sched_barrier(0);
  asm volatile("s_waitcnt lgkmcnt(0)" ::: "memory");
  __builtin_amdgcn_sched_barrier(0);
  __builtin_amdgcn_s_barrier();
  __builtin_amdgcn_sched_barrier(0);
}
__device__ __forceinline__ void bar_only() {
  __builtin_amdgcn_sched_barrier(0);
  __builtin_amdgcn_s_barrier();
  __builtin_amdgcn_sched_barrier(0);
}

// ---- K0: W1/W2/W3 (f32, [k][n]) -> MFMA-fragment-packed bf16 ----
// dst u16 index = ((L*16+nt)*8+ks)*512 + lane*8 + j  (lane = g*16+ml).
// A wave's A-fragment load (nt,ks) is then 64 lanes x 16B = 1 KB contiguous.
__global__ void k_prep(const float* __restrict__ W1, const float* __restrict__ W2,
                       const float* __restrict__ W3, u16* __restrict__ wt) {
  const int b = blockIdx.x;
  const int m = b >> 8;          // which matrix
  const int n = b & 255;         // output unit
  const int k = threadIdx.x;     // input unit
  const float* W = (m == 0) ? W1 : ((m == 1) ? W2 : W3);
  const int nt = n >> 4, ml = n & 15;
  const int ks = k >> 5, g = (k >> 3) & 3, j = k & 7;
  const int lane = g * 16 + ml;
  wt[(((m * 16 + nt) * 8 + ks) << 9) + lane * 8 + j] = f2bf(W[k * 256 + n]);
}

// One MLP layer on buf (in place): champion inner geometry.
// Wave w owns n in [w*32, w*32+32) for all 128 rows.
__device__ __forceinline__ void mlp_layer(
    int Lidx, u16* buf, const u16* __restrict__ wt, const float* bias_s,
    int w, int lane, int ml, int g, int wn0, int swz, int bofs)
{
  const char* wl = (const char*)wt +
      ((size_t)(Lidx * 16 + w * 2) * 8) * 1024 + lane * 16;
  const float* bs = bias_s + Lidx * HID;
  char* const hb  = (char*)buf;
  char* const hbr = hb + (size_t)ml * 512;

  f32x4 acc[2][8];   // [nf][rf] = 64 AGPR
  #pragma unroll
  for (int nf = 0; nf < 2; ++nf)
    #pragma unroll
    for (int rf = 0; rf < 8; ++rf)
      acc[nf][rf] = (f32x4){0.f, 0.f, 0.f, 0.f};

  __builtin_amdgcn_s_setprio(1);
  #pragma unroll
  for (int ks = 0; ks < 8; ++ks) {
    bf16x8 a[2];
    #pragma unroll
    for (int nf = 0; nf < 2; ++nf)
      a[nf] = *(const bf16x8*)(wl + (nf * 8 + ks) * 1024);       // 1KB coalesced
    #pragma unroll
    for (int rh = 0; rh < 2; ++rh) {
      bf16x8 bq[4];
      #pragma unroll
      for (int rj = 0; rj < 4; ++rj)
        bq[rj] = *(const bf16x8*)(hbr + (rh * 4 + rj) * 8192 + ((ks * 64) ^ bofs));
      #pragma unroll
      for (int nf = 0; nf < 2; ++nf)
        #pragma unroll
        for (int rj = 0; rj < 4; ++rj)
          acc[nf][rh * 4 + rj] = __builtin_amdgcn_mfma_f32_16x16x32_bf16(
              a[nf], bq[rj], acc[nf][rh * 4 + rj], 0, 0, 0);
    }
  }
  __builtin_amdgcn_s_setprio(0);
  bar_only();   // all reads of buf done -> safe to overwrite in place

  #pragma unroll
  for (int nf = 0; nf < 2; ++nf) {
    const int n0 = wn0 + nf * 16 + g * 4;
    const f32x4 bb = *(const f32x4*)(bs + n0);
    #pragma unroll
    for (int rf = 0; rf < 8; ++rf) {
      const int r = rf * 16 + ml;
      bf16x4 hv;
      #pragma unroll
      for (int q = 0; q < 4; ++q) {
        float x = acc[nf][rf][q] + bb[q];
        x = fmaxf(x, 0.f);
        hv[q] = (short)f2bf(x);
      }
      *(bf16x4*)(hb + r * 512 + ((n0 * 2) ^ swz)) = hv;
    }
  }
  bar_lgkm();
}

// ---- K1: fused X-concat/X_states write + 3-layer MLP + fused head ----
// r16 champion; single delta: stage re-mapped so every X_states nt-store
// instruction is lane-contiguous (32 lanes x 16B = 512B span -> full 64B
// lines, no partial-line write amplification). LDS layout bit-identical
// (swizzle bits 4-7 commute with 8B-granular writes).
__global__ __launch_bounds__(512, 4) void k_main(
    const float* __restrict__ g_emb, const float* __restrict__ cand,
    const int* __restrict__ bidx,
    const float* __restrict__ b1, const float* __restrict__ b2,
    const float* __restrict__ b3, const float* __restrict__ Wf,
    const float* __restrict__ bfp, const u16* __restrict__ wt,
    float* __restrict__ out)
{
  __shared__ __align__(16) u16 hbuf[RB * HID];   // 64 KB, chunk-XOR swizzled
  __shared__ float bias_s[3 * HID];
  __shared__ float bf_s;

  const int tid = threadIdx.x;
  const int r0  = blockIdx.x * RB;

  if (tid < HID) {
    bias_s[tid]           = b1[tid];
    bias_s[HID + tid]     = b2[tid];
    bias_s[2 * HID + tid] = b3[tid];
    if (tid == 0) bf_s = bfp[0];
  }

  // ---- stage X (concat) into LDS bf16 swizzled; write X_states f32 (nt) ----
  // Thread kc owns floats [kc*4, kc*4+4) (g_emb half) and [128+kc*4, ...)
  // (cand half): each global store instruction covers a contiguous 512B
  // span across lanes 0-31 / 32-63.
  {
    const int kc   = tid & 31;    // 4-float chunk index within each 128-half
    const int row0 = tid >> 5;    // 0..15
    char* l0 = (char*)hbuf;
    int bpre[8];
    #pragma unroll
    for (int i = 0; i < 8; ++i)
      bpre[i] = bidx[r0 + row0 + i * 16];   // break dependent-load chain
    #pragma unroll
    for (int i = 0; i < 8; ++i) {
      const int row = row0 + i * 16;        // 0..127
      const int r   = r0 + row;
      const int swzr = (row & 15) << 4;
      f32x4 vg = *(const f32x4*)(g_emb + (size_t)bpre[i] * EMB + kc * 4);
      f32x4 vc = *(const f32x4*)(cand  + (size_t)r * EMB + kc * 4);
      float* dst = out + OUT_XS + (size_t)r * (2 * EMB);
      __builtin_nontemporal_store(vg, (f32x4*)(dst + kc * 4));        // 512B/instr
      __builtin_nontemporal_store(vc, (f32x4*)(dst + EMB + kc * 4));  // 512B/instr
      bf16x4 hg, hc;
      #pragma unroll
      for (int q = 0; q < 4; ++q) {
        hg[q] = (short)f2bf(vg[q]);
        hc[q] = (short)f2bf(vc[q]);
      }
      *(bf16x4*)(l0 + row * 512 + ((kc * 8) ^ swzr))        = hg;
      *(bf16x4*)(l0 + row * 512 + ((256 + kc * 8) ^ swzr))  = hc;
    }
  }
  bar_lgkm();

  const int lane = tid & 63;
  const int w    = tid >> 6;          // 0..7
  const int ml   = lane & 15;
  const int g    = lane >> 4;         // 0..3
  const int wn0  = w * 32;            // n-offset: 2 tiles of 16 per wave

  const int swz  = ml << 4;                 // row-swizzle ((rf*16+ml)&15 == ml)
  const int bofs = (g * 16) ^ swz;          // k-chunk xor per lane
  char* const hb  = (char*)hbuf;
  const char* const hbr = hb + (size_t)ml * 512;  // B-read base

  mlp_layer(0, hbuf, wt, bias_s, w, lane, ml, g, wn0, swz, bofs);
  mlp_layer(1, hbuf, wt, bias_s, w, lane, ml, g, wn0, swz, bofs);

  // ---- layer 3 + head, fused: h3 stays in registers ----
  {
    const char* wl = (const char*)wt +
        ((size_t)(2 * 16 + w * 2) * 8) * 1024 + lane * 16;

    f32x4 acc[2][8];
    #pragma unroll
    for (int nf = 0; nf < 2; ++nf)
      #pragma unroll
      for (int rf = 0; rf < 8; ++rf)
        acc[nf][rf] = (f32x4){0.f, 0.f, 0.f, 0.f};

    __builtin_amdgcn_s_setprio(1);
    #pragma unroll
    for (int ks = 0; ks < 8; ++ks) {
      bf16x8 a[2];
      #pragma unroll
      for (int nf = 0; nf < 2; ++nf)
        a[nf] = *(const bf16x8*)(wl + (nf * 8 + ks) * 1024);
      #pragma unroll
      for (int rh = 0; rh < 2; ++rh) {
        bf16x8 bq[4];
        #pragma unroll
        for (int rj = 0; rj < 4; ++rj)
          bq[rj] = *(const bf16x8*)(hbr + (rh * 4 + rj) * 8192 + ((ks * 64) ^ bofs));
        #pragma unroll
        for (int nf = 0; nf < 2; ++nf)
          #pragma unroll
          for (int rj = 0; rj < 4; ++rj)
            acc[nf][rh * 4 + rj] = __builtin_amdgcn_mfma_f32_16x16x32_bf16(
                a[nf], bq[rj], acc[nf][rh * 4 + rj], 0, 0, 0);
      }
    }
    __builtin_amdgcn_s_setprio(0);
    bar_only();   // all h2 reads done -> hbuf reusable as reduction pad

    // load wf/bias fragments AFTER the barrier (short liveness, no spill)
    const float* bs = bias_s + 2 * HID;
    const f32x4 bb0 = *(const f32x4*)(bs + wn0 + g * 4);
    const f32x4 bb1 = *(const f32x4*)(bs + wn0 + 16 + g * 4);
    const f32x4 wf0 = *(const f32x4*)(Wf + wn0 + g * 4);
    const f32x4 wf1 = *(const f32x4*)(Wf + wn0 + 16 + g * 4);

    float* pad = (float*)hbuf;   // [128][32] f32 partials, slot-swizzled
    #pragma unroll
    for (int rf = 0; rf < 8; ++rf) {
      const int r = rf * 16 + ml;
      f32x4 x0 = acc[0][rf] + bb0;
      f32x4 x1 = acc[1][rf] + bb1;
      float p = 0.f;
      #pragma unroll
      for (int q = 0; q < 4; ++q) {
        p += fmaxf(x0[q], 0.f) * wf0[q];
        p += fmaxf(x1[q], 0.f) * wf1[q];
      }
      const int slot = (w * 4 + g) ^ ((r & 7) << 2);   // conflict-free banks
      pad[r * 32 + slot] = p;
    }
    bar_lgkm();

    // reduce: 4 threads per row sum 32 partials -> e = exp(logit)
    {
      const int row  = tid >> 2;   // 0..127
      const int part = tid & 3;
      const int sx   = (row & 7) << 2;
      f32x4 v0 = *(const f32x4*)(pad + row * 32 + ((part * 8) ^ sx));
      f32x4 v1 = *(const f32x4*)(pad + row * 32 + ((part * 8 + 4) ^ sx));
      float s = v0[0] + v0[1] + v0[2] + v0[3] + v1[0] + v1[1] + v1[2] + v1[3];
      s += __shfl_xor(s, 1);
      s += __shfl_xor(s, 2);
      if (part == 0)
        out[OUT_P + (size_t)(r0 + row)] = __expf(s + bf_s);
    }
  }
}

// ---- K2: fused segment softmax-denominator + divide + g_emb copy ----
__global__ __launch_bounds__(256) void k_soft(
    const float* __restrict__ g_emb, const int* __restrict__ bidx,
    float* __restrict__ out)
{
  const int b   = blockIdx.x;
  const int tid = threadIdx.x;
  __shared__ float ws[4];
  __shared__ float sden;

  int lo = 0, hi = N_CAND;
  while (lo < hi) { int m = (lo + hi) >> 1; if (bidx[m] < b) lo = m + 1; else hi = m; }
  int lo2 = lo, hi2 = N_CAND;
  while (lo2 < hi2) { int m = (lo2 + hi2) >> 1; if (bidx[m] < b + 1) lo2 = m + 1; else hi2 = m; }

  float s = 0.f;
  for (int i = lo + tid; i < lo2; i += 256) s += out[OUT_P + (size_t)i];
  #pragma unroll
  for (int off = 32; off > 0; off >>= 1) s += __shfl_down(s, off);
  if ((tid & 63) == 0) ws[tid >> 6] = s;
  __syncthreads();
  if (tid == 0) sden = ws[0] + ws[1] + ws[2] + ws[3];
  __syncthreads();
  const float d = sden;
  for (int i = lo + tid; i < lo2; i += 256)
    out[OUT_P + (size_t)i] = out[OUT_P + (size_t)i] / d;

  if (tid < 32) {
    f32x4 v = *(const f32x4*)(g_emb + (size_t)b * EMB + tid * 4);
    *(f32x4*)(out + (size_t)b * EMB + tid * 4) = v;
  }
}

extern "C" void kernel_launch(void* const* d_in, const int* in_sizes, int n_in,
                              void* d_out, int out_size, void* d_ws, size_t ws_size,
                              hipStream_t stream)
{
  const float* g_emb = (const float*)d_in[0];
  const float* cand  = (const float*)d_in[1];
  const float* W1    = (const float*)d_in[2];
  const float* b1    = (const float*)d_in[3];
  const float* W2    = (const float*)d_in[4];
  const float* b2    = (const float*)d_in[5];
  const float* W3    = (const float*)d_in[6];
  const float* b3    = (const float*)d_in[7];
  const float* Wf    = (const float*)d_in[8];
  const float* bfp   = (const float*)d_in[9];
  const int*   bidx  = (const int*)d_in[10];
  float* out = (float*)d_out;

  u16* wt = (u16*)d_ws;    // 3 * 128 KB packed bf16 weights

  k_prep <<<768, 256, 0, stream>>>(W1, W2, W3, wt);
  k_main <<<NBLK, 512, 0, stream>>>(g_emb, cand, bidx, b1, b2, b3, Wf, bfp, wt, out);
  k_soft <<<BGR, 256, 0, stream>>>(g_emb, bidx, out);
}